// Round 1
// baseline (974.406 us; speedup 1.0000x reference)
//
#include <hip/hip_runtime.h>

#define N 128
#define NITER 60

// One block per batch row. 256 threads; thread (tr,tc) owns the 8x8 tile
// z[tr*8 .. tr*8+7][tc*8 .. tc*8+7] and the matching w=A tile in registers.
// LDS only carries per-tile partial sums, y, and sparsemax scratch.
__global__ __launch_bounds__(256, 2)
void gfusedmax_kernel(const float* __restrict__ x,
                      const float* __restrict__ A,
                      float* __restrict__ out)
{
    const int b   = blockIdx.x;
    const int tid = threadIdx.x;
    const int tr  = tid >> 4;   // 0..15
    const int tc  = tid & 15;   // 0..15
    const int i0  = tr * 8;
    const int j0  = tc * 8;

    // stride 129: partial-write banks (tc + 8tr + r) % 32 -> 2-way (free)
    __shared__ float rowpart[16 * 129];   // [tc][i]
    // stride 132: partial-write banks (4tr + 8tc + c) % 32 -> 2-way (free)
    __shared__ float colpart[16 * 132];   // [tr][j]
    __shared__ float yv[N];
    __shared__ float sorted[N];
    __shared__ float red[8];

    const float step = 1.0f / 256.0f;   // 1/(2N)

    // ---- load w = lam*A (lam=1) tile into registers, init z=0 ----
    float w[8][8];
    float z[8][8];
    const float* Ab = A + (size_t)b * N * N;
    #pragma unroll
    for (int r = 0; r < 8; ++r) {
        const float4* src = (const float4*)(Ab + (size_t)(i0 + r) * N + j0);
        float4 p0 = src[0];
        float4 p1 = src[1];
        w[r][0] = p0.x; w[r][1] = p0.y; w[r][2] = p0.z; w[r][3] = p0.w;
        w[r][4] = p1.x; w[r][5] = p1.y; w[r][6] = p1.z; w[r][7] = p1.w;
        #pragma unroll
        for (int c = 0; c < 8; ++c) z[r][c] = 0.0f;
    }

    float xi = 0.0f;
    if (tid < N) xi = x[(size_t)b * N + tid];

    float yfin = 0.0f;   // this thread's final primal value (tid < 128)

    for (int it = 0; it <= NITER; ++it) {
        // (a) in-register partial row/col sums of the 8x8 tile
        float pr[8], pc[8];
        #pragma unroll
        for (int r = 0; r < 8; ++r) pr[r] = 0.0f;
        #pragma unroll
        for (int c = 0; c < 8; ++c) pc[c] = 0.0f;
        #pragma unroll
        for (int r = 0; r < 8; ++r)
            #pragma unroll
            for (int c = 0; c < 8; ++c) {
                pr[r] += z[r][c];
                pc[c] += z[r][c];
            }
        // (b) publish partials
        #pragma unroll
        for (int r = 0; r < 8; ++r) rowpart[tc * 129 + i0 + r] = pr[r];
        #pragma unroll
        for (int c = 0; c < 8; ++c) colpart[tr * 132 + j0 + c] = pc[c];
        __syncthreads();

        // (c) threads 0..127: reduce 16 partials each, publish y
        if (tid < N) {
            float rs = 0.0f, cs = 0.0f;
            #pragma unroll
            for (int k = 0; k < 16; ++k) rs += rowpart[k * 129 + tid];
            #pragma unroll
            for (int k = 0; k < 16; ++k) cs += colpart[k * 132 + tid];
            float y = xi - rs + cs;
            yv[tid] = y;
            yfin = y;
        }
        __syncthreads();
        if (it == NITER) break;

        // (d) dual update: z = clip(z + step*(y_i - y_j), -w, w)
        float dr[8], ec[8];
        #pragma unroll
        for (int r = 0; r < 8; ++r) dr[r] = step * yv[i0 + r];
        #pragma unroll
        for (int c = 0; c < 8; ++c) ec[c] = step * yv[j0 + c];
        #pragma unroll
        for (int r = 0; r < 8; ++r)
            #pragma unroll
            for (int c = 0; c < 8; ++c) {
                float t = z[r][c] + dr[r] - ec[c];
                z[r][c] = __builtin_amdgcn_fmed3f(t, -w[r][c], w[r][c]);
            }
    }

    // ---- sparsemax over yv[0..127] ----
    // rank by comparison (ties broken by index -> rank is a permutation)
    float v = yfin;
    if (tid < N) {
        int rk = 0;
        for (int k = 0; k < N; ++k) {
            float u = yv[k];
            rk += (u > v) || (u == v && k < tid);
        }
        sorted[rk] = v;
    }
    __syncthreads();

    float s = 0.0f, csum = 0.0f;
    if (tid < N) {
        s = sorted[tid];
        for (int m = 0; m < N; ++m) {           // uniform index -> LDS broadcast
            float t = sorted[m];
            if (m <= tid) csum += t;            // inclusive prefix at sorted pos tid
        }
    }
    bool mask = (tid < N) && (1.0f + (float)(tid + 1) * s > csum);
    float aRed = mask ? s : 0.0f;
    float bRed = mask ? 1.0f : 0.0f;
    #pragma unroll
    for (int off = 32; off >= 1; off >>= 1) {
        aRed += __shfl_down(aRed, off, 64);
        bRed += __shfl_down(bRed, off, 64);
    }
    const int wid = tid >> 6;
    if ((tid & 63) == 0) { red[wid * 2] = aRed; red[wid * 2 + 1] = bRed; }
    __syncthreads();
    const float tau = (red[0] + red[2] + red[4] + red[6] - 1.0f)
                    / (red[1] + red[3] + red[5] + red[7]);
    if (tid < N) out[(size_t)b * N + tid] = fmaxf(v - tau, 0.0f);
}

extern "C" void kernel_launch(void* const* d_in, const int* in_sizes, int n_in,
                              void* d_out, int out_size, void* d_ws, size_t ws_size,
                              hipStream_t stream) {
    const float* x = (const float*)d_in[0];
    const float* A = (const float*)d_in[1];
    float* out = (float*)d_out;
    const int B = in_sizes[0] / N;   // 4096 rows
    gfusedmax_kernel<<<B, 256, 0, stream>>>(x, A, out);
}

// Round 2
// 970.442 us; speedup vs baseline: 1.0041x; 1.0041x over previous
//
#include <hip/hip_runtime.h>

#define N 128
#define NITER 60
#define PSTR 132   // partial-array stride: multiple of 4 floats -> 16B-aligned rows -> b128 LDS ops

// One block per batch row. 256 threads; thread (tr,tc) owns the 8x8 tile
// z[8tr..8tr+7][8tc..8tc+7] and matching w=A tile in registers.
// launch_bounds(256,1): ~180 live floats MUST stay in arch VGPRs — (256,2)
// made the compiler pick 96 VGPRs + AGPR shuttling (2x VALU inflation, R1).
__global__ __launch_bounds__(256, 1)
void gfusedmax_kernel(const float* __restrict__ x,
                      const float* __restrict__ A,
                      float* __restrict__ out)
{
    const int b   = blockIdx.x;
    const int tid = threadIdx.x;
    const int tr  = tid >> 4;   // 0..15
    const int tc  = tid & 15;   // 0..15
    const int i0  = tr * 8;
    const int j0  = tc * 8;

    __shared__ float rowpart[16 * PSTR];   // [tc][i]
    __shared__ float colpart[16 * PSTR];   // [tr][j]
    __shared__ float yv[N];                // step*y during loop, raw y at end
    __shared__ float sorted[N];
    __shared__ float red[8];

    const float step = 1.0f / 256.0f;   // 1/(2N), exact power of two

    // ---- load w = lam*A (lam=1) tile into registers, init z=0 ----
    float w[8][8];
    float z[8][8];
    const float* Ab = A + (size_t)b * N * N;
    #pragma unroll
    for (int r = 0; r < 8; ++r) {
        const float4* src = (const float4*)(Ab + (size_t)(i0 + r) * N + j0);
        float4 p0 = src[0];
        float4 p1 = src[1];
        w[r][0] = p0.x; w[r][1] = p0.y; w[r][2] = p0.z; w[r][3] = p0.w;
        w[r][4] = p1.x; w[r][5] = p1.y; w[r][6] = p1.z; w[r][7] = p1.w;
        #pragma unroll
        for (int c = 0; c < 8; ++c) z[r][c] = 0.0f;
    }

    float xi = 0.0f;
    if (tid < N) xi = x[(size_t)b * N + tid];

    // partial row/col sums of z, maintained by the fused update loop (z=0 now)
    float pr[8], pc[8];
    #pragma unroll
    for (int r = 0; r < 8; ++r) { pr[r] = 0.0f; pc[r] = 0.0f; }

    float yfin = 0.0f;   // final primal value for tid < 128

    for (int it = 0; it <= NITER; ++it) {
        // (a) publish partial sums (contiguous 8-float runs, 16B-aligned -> b128)
        #pragma unroll
        for (int r = 0; r < 8; ++r) rowpart[tc * PSTR + i0 + r] = pr[r];
        #pragma unroll
        for (int c = 0; c < 8; ++c) colpart[tr * PSTR + j0 + c] = pc[c];
        __syncthreads();

        // (b) threads 0..127 reduce 32 partials, publish step*y (raw y on last)
        if (tid < N) {
            float rs = 0.0f, cs = 0.0f;
            #pragma unroll
            for (int k = 0; k < 16; ++k) rs += rowpart[k * PSTR + tid];
            #pragma unroll
            for (int k = 0; k < 16; ++k) cs += colpart[k * PSTR + tid];
            float y = xi - rs + cs;
            yfin = y;
            // scaling by 2^-8 is exact, so step*yi - step*yj == step*(yi-yj)
            yv[tid] = (it == NITER) ? y : step * y;
        }
        __syncthreads();
        if (it == NITER) break;

        // (c) fused dual update + partial-sum accumulation (5 VALU/element)
        float dr[8], ec[8];
        #pragma unroll
        for (int r = 0; r < 8; ++r) dr[r] = yv[i0 + r];   // contiguous -> b128
        #pragma unroll
        for (int c = 0; c < 8; ++c) ec[c] = yv[j0 + c];
        #pragma unroll
        for (int r = 0; r < 8; ++r) pr[r] = 0.0f;
        #pragma unroll
        for (int c = 0; c < 8; ++c) pc[c] = 0.0f;
        #pragma unroll
        for (int r = 0; r < 8; ++r)
            #pragma unroll
            for (int c = 0; c < 8; ++c) {
                float t = z[r][c] + dr[r] - ec[c];
                float zn = __builtin_amdgcn_fmed3f(t, -w[r][c], w[r][c]);
                z[r][c] = zn;
                pr[r] += zn;
                pc[c] += zn;
            }
    }

    // ---- sparsemax over yv[0..127] (raw y) ----
    float v = yfin;
    if (tid < N) {
        int rk = 0;
        for (int k = 0; k < N; ++k) {
            float u = yv[k];
            rk += (u > v) || (u == v && k < tid);
        }
        sorted[rk] = v;   // rank is a permutation (ties broken by index)
    }
    __syncthreads();

    float s = 0.0f, csum = 0.0f;
    if (tid < N) {
        s = sorted[tid];
        for (int m = 0; m < N; ++m) {            // uniform index -> LDS broadcast
            float t = sorted[m];
            if (m <= tid) csum += t;             // inclusive prefix at sorted pos
        }
    }
    bool mask = (tid < N) && (1.0f + (float)(tid + 1) * s > csum);
    float aRed = mask ? s : 0.0f;
    float bRed = mask ? 1.0f : 0.0f;
    #pragma unroll
    for (int off = 32; off >= 1; off >>= 1) {
        aRed += __shfl_down(aRed, off, 64);
        bRed += __shfl_down(bRed, off, 64);
    }
    const int wid = tid >> 6;
    if ((tid & 63) == 0) { red[wid * 2] = aRed; red[wid * 2 + 1] = bRed; }
    __syncthreads();
    const float tau = (red[0] + red[2] + red[4] + red[6] - 1.0f)
                    / (red[1] + red[3] + red[5] + red[7]);
    if (tid < N) out[(size_t)b * N + tid] = fmaxf(v - tau, 0.0f);
}

extern "C" void kernel_launch(void* const* d_in, const int* in_sizes, int n_in,
                              void* d_out, int out_size, void* d_ws, size_t ws_size,
                              hipStream_t stream) {
    const float* x = (const float*)d_in[0];
    const float* A = (const float*)d_in[1];
    float* out = (float*)d_out;
    const int B = in_sizes[0] / N;   // 4096 rows
    gfusedmax_kernel<<<B, 256, 0, stream>>>(x, A, out);
}